// Round 6
// baseline (210.416 us; speedup 1.0000x reference)
//
#include <hip/hip_runtime.h>
#include <hip/hip_bf16.h>
#include <stdint.h>

typedef __bf16 bf16x8 __attribute__((ext_vector_type(8)));
typedef float f32x4 __attribute__((ext_vector_type(4)));
typedef unsigned short u16;
typedef unsigned int u32;

struct __align__(8) us4 { u16 x, y, z, w; };
struct __align__(16) us8 { u16 v[8]; };

#define LOG2E 1.44269504088896f
#define QSCALE (0.125f * LOG2E)

// async global->LDS, 16B per lane. LDS dest = wave-uniform base + lane*16.
__device__ __forceinline__ void async_load16(const void* g, void* l) {
    __builtin_amdgcn_global_load_lds(
        (const __attribute__((address_space(1))) u32*)(uintptr_t)g,
        (__attribute__((address_space(3))) u32*)(u32)(uintptr_t)l,
        16, 0, 0);
}

__device__ __forceinline__ u16 f2bfbits(float f) {
    __bf16 h = (__bf16)f;   // RNE fptrunc
    return __builtin_bit_cast(u16, h);
}

// Single fused fp32->bf16 convert over all 6 inputs. 8 elems/thread.
__global__ __launch_bounds__(256) void convert_all(
    const float* __restrict__ x, const float* __restrict__ ctx,
    const float* __restrict__ wq, const float* __restrict__ wk,
    const float* __restrict__ wv, const float* __restrict__ wo,
    u16* __restrict__ xb, u16* __restrict__ ctxb, u16* __restrict__ wqb,
    u16* __restrict__ wkb, u16* __restrict__ wvb, u16* __restrict__ wob) {
    int i = blockIdx.x * 256 + threadIdx.x;
    const float* s; u16* d; int j;
    if (i < 524288)        { s = x;   d = xb;   j = i; }
    else if (i < 1572864)  { s = ctx; d = ctxb; j = i - 524288; }
    else if (i < 1703936)  { s = wq;  d = wqb;  j = i - 1572864; }
    else if (i < 1736704)  { s = wk;  d = wkb;  j = i - 1703936; }
    else if (i < 1769472)  { s = wv;  d = wvb;  j = i - 1736704; }
    else                   { s = wo;  d = wob;  j = i - 1769472; }
    const float4* sp = (const float4*)s + (size_t)j * 2;
    float4 a = sp[0], b = sp[1];
    us8 o;
    o.v[0] = f2bfbits(a.x); o.v[1] = f2bfbits(a.y);
    o.v[2] = f2bfbits(a.z); o.v[3] = f2bfbits(a.w);
    o.v[4] = f2bfbits(b.x); o.v[5] = f2bfbits(b.y);
    o.v[6] = f2bfbits(b.z); o.v[7] = f2bfbits(b.w);
    *(us8*)(d + (size_t)j * 8) = o;
}

// Fused Q/K/V projections, 128x128 tiles (m97 structure), 512 blocks = 2/CU.
// bid<256: Q (M=4096,N=1024), epilogue * QSCALE, natural layout.
// bid<384: K -> k2 [((b*4+g)*2048+t)*64+d].  else: V -> vT [((b*4+g)*64+d)*2048+t].
__global__ __launch_bounds__(256) void proj_qkv(
    const u16* __restrict__ xb, const u16* __restrict__ ctxb,
    const u16* __restrict__ Wqb, const u16* __restrict__ Wkb,
    const u16* __restrict__ Wvb,
    u16* __restrict__ q, u16* __restrict__ k2, u16* __restrict__ vT) {
    __shared__ u16 As[128 * 64];
    __shared__ u16 Bs[128 * 64];
    const int tid = threadIdx.x;
    const int w = tid >> 6, lane = tid & 63, quad = lane >> 4, id = lane & 15;
    const int wr = (w >> 1) * 64, wc = (w & 1) * 64;
    const int lrow = lane >> 3, lcol = (lane & 7) * 8;

    const int bid = blockIdx.x;
    const u16 *A, *Bm;
    int mtile, ntile, mode;
    if (bid < 256) {
        mode = 0; A = xb; Bm = Wqb;
        mtile = (bid >> 3) * 128; ntile = (bid & 7) * 128;
    } else if (bid < 384) {
        int s2 = bid - 256;
        mode = 1; A = ctxb; Bm = Wkb;
        mtile = (s2 >> 1) * 128; ntile = (s2 & 1) * 128;
    } else {
        int s2 = bid - 384;
        mode = 2; A = ctxb; Bm = Wvb;
        mtile = (s2 >> 1) * 128; ntile = (s2 & 1) * 128;
    }

    f32x4 acc[4][4];
#pragma unroll
    for (int i = 0; i < 4; i++)
#pragma unroll
        for (int j = 0; j < 4; j++) acc[i][j] = (f32x4){0.f, 0.f, 0.f, 0.f};

    for (int k0 = 0; k0 < 1024; k0 += 64) {
        __syncthreads();
#pragma unroll
        for (int is = 0; is < 4; is++) {
            int r = is * 32 + w * 8 + lrow;
            async_load16(A + (size_t)(mtile + r) * 1024 + k0 + lcol, &As[(is * 32 + w * 8) * 64]);
        }
#pragma unroll
        for (int is = 0; is < 4; is++) {
            int r = is * 32 + w * 8 + lrow;
            async_load16(Bm + (size_t)(ntile + r) * 1024 + k0 + lcol, &Bs[(is * 32 + w * 8) * 64]);
        }
        __syncthreads();
#pragma unroll
        for (int kk = 0; kk < 2; kk++) {
            bf16x8 af[4], bfr[4];
#pragma unroll
            for (int i = 0; i < 4; i++)
                af[i] = *(const bf16x8*)&As[(wr + i * 16 + id) * 64 + kk * 32 + quad * 8];
#pragma unroll
            for (int j = 0; j < 4; j++)
                bfr[j] = *(const bf16x8*)&Bs[(wc + j * 16 + id) * 64 + kk * 32 + quad * 8];
#pragma unroll
            for (int i = 0; i < 4; i++)
#pragma unroll
                for (int j = 0; j < 4; j++)
                    acc[i][j] = __builtin_amdgcn_mfma_f32_16x16x32_bf16(af[i], bfr[j], acc[i][j], 0, 0, 0);
        }
    }

#pragma unroll
    for (int i = 0; i < 4; i++)
#pragma unroll
        for (int j = 0; j < 4; j++) {
            int mbase = mtile + wr + i * 16 + quad * 4;
            int n = ntile + wc + j * 16 + id;
            if (mode == 2) {
                int b = mbase >> 11, t = mbase & 2047;
                int g = n >> 6, d = n & 63;
                us4 pk;
                pk.x = f2bfbits(acc[i][j][0]);
                pk.y = f2bfbits(acc[i][j][1]);
                pk.z = f2bfbits(acc[i][j][2]);
                pk.w = f2bfbits(acc[i][j][3]);
                *(us4*)&vT[((size_t)((b << 2) + g) * 64 + d) * 2048 + t] = pk;
            } else if (mode == 1) {
#pragma unroll
                for (int r = 0; r < 4; r++) {
                    int m = mbase + r;
                    int b = m >> 11, t = m & 2047;
                    int g = n >> 6, d = n & 63;
                    k2[((size_t)((b << 2) + g) * 2048 + t) * 64 + d] = f2bfbits(acc[i][j][r]);
                }
            } else {
#pragma unroll
                for (int r = 0; r < 4; r++)
                    q[(size_t)(mbase + r) * 1024 + n] = f2bfbits(acc[i][j][r] * QSCALE);
            }
        }
}

// Output projection, 128x128 tiles: out(f32) = o(bf16) @ Wo^T.
__global__ __launch_bounds__(256) void gemm_out(const u16* __restrict__ A,
                                                const u16* __restrict__ Bm,
                                                float* __restrict__ C) {
    __shared__ u16 As[128 * 64];
    __shared__ u16 Bs[128 * 64];
    const int tid = threadIdx.x;
    const int w = tid >> 6, lane = tid & 63, quad = lane >> 4, id = lane & 15;
    const int mtile = blockIdx.y * 128, ntile = blockIdx.x * 128;
    const int wr = (w >> 1) * 64, wc = (w & 1) * 64;
    const int lrow = lane >> 3, lcol = (lane & 7) * 8;

    f32x4 acc[4][4];
#pragma unroll
    for (int i = 0; i < 4; i++)
#pragma unroll
        for (int j = 0; j < 4; j++) acc[i][j] = (f32x4){0.f, 0.f, 0.f, 0.f};

    for (int k0 = 0; k0 < 1024; k0 += 64) {
        __syncthreads();
#pragma unroll
        for (int is = 0; is < 4; is++) {
            int r = is * 32 + w * 8 + lrow;
            async_load16(A + (size_t)(mtile + r) * 1024 + k0 + lcol, &As[(is * 32 + w * 8) * 64]);
        }
#pragma unroll
        for (int is = 0; is < 4; is++) {
            int r = is * 32 + w * 8 + lrow;
            async_load16(Bm + (size_t)(ntile + r) * 1024 + k0 + lcol, &Bs[(is * 32 + w * 8) * 64]);
        }
        __syncthreads();
#pragma unroll
        for (int kk = 0; kk < 2; kk++) {
            bf16x8 af[4], bfr[4];
#pragma unroll
            for (int i = 0; i < 4; i++)
                af[i] = *(const bf16x8*)&As[(wr + i * 16 + id) * 64 + kk * 32 + quad * 8];
#pragma unroll
            for (int j = 0; j < 4; j++)
                bfr[j] = *(const bf16x8*)&Bs[(wc + j * 16 + id) * 64 + kk * 32 + quad * 8];
#pragma unroll
            for (int i = 0; i < 4; i++)
#pragma unroll
                for (int j = 0; j < 4; j++)
                    acc[i][j] = __builtin_amdgcn_mfma_f32_16x16x32_bf16(af[i], bfr[j], acc[i][j], 0, 0, 0);
        }
    }

#pragma unroll
    for (int i = 0; i < 4; i++)
#pragma unroll
        for (int j = 0; j < 4; j++) {
            int mbase = mtile + wr + i * 16 + quad * 4;
            int n = ntile + wc + j * 16 + id;
#pragma unroll
            for (int r = 0; r < 4; r++)
                C[(size_t)(mbase + r) * 1024 + n] = acc[i][j][r];
        }
}

// Flash attention, no-max softmax, REGISTER-ONLY P path (unchanged from R5).
__global__ __launch_bounds__(256, 2) void attn_kernel(const u16* __restrict__ q,
                                                      const u16* __restrict__ k2,
                                                      const u16* __restrict__ vT,
                                                      u16* __restrict__ o) {
    __shared__ u16 Ks[2][64 * 64];
    __shared__ u16 Vt[2][64 * 64];
    const int tid = threadIdx.x;
    const int w = tid >> 6, lane = tid & 63, quad = lane >> 4, id = lane & 15;

    const int bid = blockIdx.x;
    const int xcd = bid & 7, slot = bid >> 3;
    const int bg = xcd * 2 + (slot >> 5);
    const int inner = slot & 31;
    const int b = bg >> 2, g = bg & 3;
    const int h = g * 4 + (inner >> 3);
    const int s0 = (inner & 7) * 128;

    const int stgswz = (((lane & 7) ^ (lane >> 3) ^ ((w & 1) << 2))) * 8;
    int kfkey[2];
#pragma unroll
    for (int c = 0; c < 2; c++)
        kfkey[c] = (id & 3) | (((c ^ ((id >> 2) & 1)) & 1) << 2);
    const int vkey = (id & 7) ^ (((id >> 3) & 1) << 2);
    const int trow_base = ((id & 12) << 1) + (id & 3);

    bf16x8 qf[2][2];
#pragma unroll
    for (int rb = 0; rb < 2; rb++) {
        const size_t base = ((size_t)(b * 1024 + s0 + w * 32 + rb * 16 + id)) * 1024 + h * 64;
        qf[rb][0] = *(const bf16x8*)&q[base + quad * 8];
        qf[rb][1] = *(const bf16x8*)&q[base + 32 + quad * 8];
    }

    bf16x8 ones;
    {
        __bf16 one = (__bf16)1.0f;
#pragma unroll
        for (int i = 0; i < 8; i++) ones[i] = one;
    }

    f32x4 acc[2][4], accl[2];
#pragma unroll
    for (int rb = 0; rb < 2; rb++) {
        accl[rb] = (f32x4){0.f, 0.f, 0.f, 0.f};
#pragma unroll
        for (int i = 0; i < 4; i++) acc[rb][i] = (f32x4){0.f, 0.f, 0.f, 0.f};
    }

    const size_t kbase = ((size_t)(b * 4 + g)) * 2048 * 64;
    const size_t vbase = ((size_t)(b * 4 + g)) * 64 * 2048;

    auto stage = [&](int t0, int buf) {
#pragma unroll
        for (int is = 0; is < 2; is++) {
            int tl = is * 32 + w * 8;
            async_load16(&k2[kbase + (size_t)(t0 + tl + (lane >> 3)) * 64 + stgswz],
                         &Ks[buf][tl * 64]);
        }
#pragma unroll
        for (int is = 0; is < 2; is++) {
            int dl = is * 32 + w * 8;
            async_load16(&vT[vbase + (size_t)(dl + (lane >> 3)) * 2048 + t0 + stgswz],
                         &Vt[buf][dl * 64]);
        }
    };

    stage(0, 0);
    __syncthreads();

    int cur = 0;
    for (int t0 = 0; t0 < 2048; t0 += 64) {
        if (t0 + 64 < 2048) stage(t0 + 64, cur ^ 1);

        f32x4 s[2][2][2];
#pragma unroll
        for (int kk = 0; kk < 2; kk++)
#pragma unroll
            for (int P = 0; P < 2; P++)
#pragma unroll
                for (int c = 0; c < 2; c++) {
                    int trow = P * 32 + trow_base + c * 4;
                    bf16x8 kf = *(const bf16x8*)&Ks[cur][trow * 64 + (((kk * 4 + quad) ^ kfkey[c]) * 8)];
#pragma unroll
                    for (int rb = 0; rb < 2; rb++)
                        s[rb][P][c] = __builtin_amdgcn_mfma_f32_16x16x32_bf16(
                            kf, qf[rb][kk],
                            kk ? s[rb][P][c] : (f32x4){0.f, 0.f, 0.f, 0.f}, 0, 0, 0);
                }

        bf16x8 pa[2][2];
#pragma unroll
        for (int rb = 0; rb < 2; rb++)
#pragma unroll
            for (int P = 0; P < 2; P++) {
                bf16x8 t;
#pragma unroll
                for (int c = 0; c < 2; c++)
#pragma unroll
                    for (int r = 0; r < 4; r++)
                        t[c * 4 + r] = (__bf16)__builtin_exp2f(s[rb][P][c][r]);
                pa[rb][P] = t;
            }

#pragma unroll
        for (int P = 0; P < 2; P++) {
#pragma unroll
            for (int db = 0; db < 4; db++) {
                bf16x8 vf = *(const bf16x8*)&Vt[cur][(db * 16 + id) * 64 + (((P * 4 + quad) ^ vkey) * 8)];
#pragma unroll
                for (int rb = 0; rb < 2; rb++)
                    acc[rb][db] = __builtin_amdgcn_mfma_f32_16x16x32_bf16(pa[rb][P], vf, acc[rb][db], 0, 0, 0);
            }
#pragma unroll
            for (int rb = 0; rb < 2; rb++)
                accl[rb] = __builtin_amdgcn_mfma_f32_16x16x32_bf16(pa[rb][P], ones, accl[rb], 0, 0, 0);
        }

        __syncthreads();
        cur ^= 1;
    }

#pragma unroll
    for (int rb = 0; rb < 2; rb++) {
        f32x4 inv;
#pragma unroll
        for (int r = 0; r < 4; r++) inv[r] = 1.0f / accl[rb][r];
#pragma unroll
        for (int db = 0; db < 4; db++)
#pragma unroll
            for (int r = 0; r < 4; r++) {
                int srow = s0 + w * 32 + rb * 16 + quad * 4 + r;
                o[((size_t)(b * 1024 + srow)) * 1024 + h * 64 + db * 16 + id] =
                    f2bfbits(acc[rb][db][r] * inv[r]);
            }
    }
}

extern "C" void kernel_launch(void* const* d_in, const int* in_sizes, int n_in,
                              void* d_out, int out_size, void* d_ws, size_t ws_size,
                              hipStream_t stream) {
    (void)in_sizes; (void)n_in; (void)out_size; (void)ws_size;
    const float* x   = (const float*)d_in[0];
    const float* ctx = (const float*)d_in[1];
    const float* Wq  = (const float*)d_in[2];
    const float* Wk  = (const float*)d_in[3];
    const float* Wv  = (const float*)d_in[4];
    const float* Wo  = (const float*)d_in[5];
    float* out = (float*)d_out;

    u16* xb   = (u16*)d_ws;
    u16* ctxb = xb   + 4096 * 1024;
    u16* Wqb  = ctxb + 4 * 2048 * 1024;
    u16* Wkb  = Wqb  + 1024 * 1024;
    u16* Wvb  = Wkb  + 256 * 1024;
    u16* Wob  = Wvb  + 256 * 1024;
    u16* q    = Wob  + 1024 * 1024;
    u16* k2   = q    + 4096 * 1024;
    u16* vT   = k2   + 4 * 4 * 2048 * 64;
    u16* o    = vT   + 4 * 4 * 64 * 2048;

    convert_all<<<7424, 256, 0, stream>>>(x, ctx, Wq, Wk, Wv, Wo,
                                          xb, ctxb, Wqb, Wkb, Wvb, Wob);
    proj_qkv<<<512, 256, 0, stream>>>(xb, ctxb, Wqb, Wkb, Wvb, q, k2, vT);
    attn_kernel<<<512, 256, 0, stream>>>(q, k2, vT, o);
    gemm_out<<<dim3(8, 32), 256, 0, stream>>>(o, Wob, out);
}